// Round 1
// baseline (243.938 us; speedup 1.0000x reference)
//
#include <hip/hip_runtime.h>

// entmax-1.5 over rows of [R=16384, N=4096] fp32.
// Exact threshold tau* solves sum_i max(z_i - tau, 0)^2 = 1 with z=(x-max)/2.
// We solve it with monotone (safeguarded-by-convexity) Newton from tau=-1:
//   f(tau) = sum [z-tau]_+^2  (convex, decreasing),  f(-1) >= 1 since z_max=0.
//   tau_{k+1} = tau_k + (f-1) / (2 * sum [z-tau]_+)   -- stays left of root.
// One wave (64 lanes) per row; each lane holds 64 elements in registers.

#define ROWLEN 4096
#define ELEMS 64    // per lane
#define CHUNKS 16   // float4 per lane
#define ROWS_PER_BLOCK 4

__global__ __launch_bounds__(256) void entmax15_rows_kernel(
    const float* __restrict__ x, float* __restrict__ out, int rows) {
    const int wave = threadIdx.x >> 6;  // 0..3, one row per wave
    const int lane = threadIdx.x & 63;
    const int row = blockIdx.x * ROWS_PER_BLOCK + wave;
    if (row >= rows) return;  // wave-uniform

    const float* __restrict__ xr = x + (size_t)row * ROWLEN;
    float* __restrict__ orow = out + (size_t)row * ROWLEN;

    float z[ELEMS];
    // Coalesced load: lane l takes float4 chunk (k*64 + l).
    #pragma unroll
    for (int k = 0; k < CHUNKS; ++k) {
        const float4 v = *reinterpret_cast<const float4*>(xr + (size_t)(k * 64 + lane) * 4);
        z[4 * k + 0] = v.x;
        z[4 * k + 1] = v.y;
        z[4 * k + 2] = v.z;
        z[4 * k + 3] = v.w;
    }

    // Row max (lane-local then 64-lane butterfly; all lanes end with the max).
    float m = z[0];
    #pragma unroll
    for (int i = 1; i < ELEMS; ++i) m = fmaxf(m, z[i]);
    #pragma unroll
    for (int s = 1; s < 64; s <<= 1) m = fmaxf(m, __shfl_xor(m, s, 64));

    // z = (x - max) * 0.5  -> z_max == 0
    #pragma unroll
    for (int i = 0; i < ELEMS; ++i) z[i] = (z[i] - m) * 0.5f;

    // Newton iteration for f(tau) = 1.
    float tau = -1.0f;
    for (int it = 0; it < 50; ++it) {
        float s1 = 0.0f, s2 = 0.0f;
        #pragma unroll
        for (int i = 0; i < ELEMS; ++i) {
            float t = fmaxf(z[i] - tau, 0.0f);
            s1 += t;
            s2 = fmaf(t, t, s2);
        }
        #pragma unroll
        for (int s = 1; s < 64; s <<= 1) {
            s1 += __shfl_xor(s1, s, 64);
            s2 += __shfl_xor(s2, s, 64);
        }
        const float g = s2 - 1.0f;           // >= 0 (monotone from the left)
        tau += g / (2.0f * s1);              // s1 >= -tau > 0 while tau < 0
        if (fabsf(g) < 1e-7f) break;         // wave-uniform (s2 identical on all lanes)
    }

    // Final probabilities: p = [z - tau]_+^2, normalized by (sum + 1e-8).
    float ssum = 0.0f;
    #pragma unroll
    for (int i = 0; i < ELEMS; ++i) {
        const float t = fmaxf(z[i] - tau, 0.0f);
        z[i] = t * t;  // reuse registers
        ssum += z[i];
    }
    #pragma unroll
    for (int s = 1; s < 64; s <<= 1) ssum += __shfl_xor(ssum, s, 64);
    const float inv = 1.0f / (ssum + 1e-8f);

    #pragma unroll
    for (int k = 0; k < CHUNKS; ++k) {
        float4 v;
        v.x = z[4 * k + 0] * inv;
        v.y = z[4 * k + 1] * inv;
        v.z = z[4 * k + 2] * inv;
        v.w = z[4 * k + 3] * inv;
        *reinterpret_cast<float4*>(orow + (size_t)(k * 64 + lane) * 4) = v;
    }
}

extern "C" void kernel_launch(void* const* d_in, const int* in_sizes, int n_in,
                              void* d_out, int out_size, void* d_ws, size_t ws_size,
                              hipStream_t stream) {
    const float* x = (const float*)d_in[0];
    float* out = (float*)d_out;
    const int rows = in_sizes[0] / ROWLEN;  // 16384
    const int blocks = (rows + ROWS_PER_BLOCK - 1) / ROWS_PER_BLOCK;
    entmax15_rows_kernel<<<blocks, 256, 0, stream>>>(x, out, rows);
}

// Round 2
// 113.938 us; speedup vs baseline: 2.1410x; 2.1410x over previous
//
#include <hip/hip_runtime.h>

// entmax-1.5 over rows of [R=16384, N=4096] fp32.
// tau* solves f(tau) = sum_i [z_i - tau]_+^2 = 1, z = (x - max)/2, so z_max = 0
// and tau* in [-1, 0). Newton from tau=-1 is monotone (convex decreasing f).
// Key pruning fact: all Newton iterates stay in [-1, tau*], so elements with
// z <= current iterate can never contribute again. After 2 full-width
// iterations we compact survivors (z > tau_2) into LDS (~30-80 of 4096 for
// Gaussian rows) and finish Newton on <=4 registers/lane instead of 64.

#define ROWLEN 4096
#define ELEMS 64    // per lane
#define CHUNKS 16   // float4 per lane
#define ROWS_PER_BLOCK 4
#define CAP 256     // survivor capacity per wave (fallback if exceeded)
#define SLOTS 4     // CAP / 64

__global__ __launch_bounds__(256) void entmax15_rows_kernel(
    const float* __restrict__ x, float* __restrict__ out, int rows) {
    __shared__ float surv[ROWS_PER_BLOCK][CAP];  // wave-private, no barriers
    const int wave = threadIdx.x >> 6;
    const int lane = threadIdx.x & 63;
    const int row = blockIdx.x * ROWS_PER_BLOCK + wave;
    if (row >= rows) return;  // wave-uniform

    const float* __restrict__ xr = x + (size_t)row * ROWLEN;
    float* __restrict__ orow = out + (size_t)row * ROWLEN;

    float z[ELEMS];
    #pragma unroll
    for (int k = 0; k < CHUNKS; ++k) {
        const float4 v = *reinterpret_cast<const float4*>(xr + (size_t)(k * 64 + lane) * 4);
        z[4 * k + 0] = v.x;
        z[4 * k + 1] = v.y;
        z[4 * k + 2] = v.z;
        z[4 * k + 3] = v.w;
    }

    // Row max via lane-local reduce + 64-lane butterfly.
    float m = z[0];
    #pragma unroll
    for (int i = 1; i < ELEMS; ++i) m = fmaxf(m, z[i]);
    #pragma unroll
    for (int s = 1; s < 64; s <<= 1) m = fmaxf(m, __shfl_xor(m, s, 64));

    #pragma unroll
    for (int i = 0; i < ELEMS; ++i) z[i] = (z[i] - m) * 0.5f;

    // Two full-width Newton iterations from tau = -1 (iterates stay <= tau*).
    float tau = -1.0f;
    #pragma unroll
    for (int it = 0; it < 2; ++it) {
        float s1 = 0.0f, s2 = 0.0f;
        #pragma unroll
        for (int i = 0; i < ELEMS; ++i) {
            const float t = fmaxf(z[i] - tau, 0.0f);
            s1 += t;
            s2 = fmaf(t, t, s2);
        }
        #pragma unroll
        for (int s = 1; s < 64; s <<= 1) {
            s1 += __shfl_xor(s1, s, 64);
            s2 += __shfl_xor(s2, s, 64);
        }
        tau += (s2 - 1.0f) / fmaxf(2.0f * s1, 1e-20f);
    }

    // Count survivors (z > tau) and exclusive-scan their positions.
    int c = 0;
    #pragma unroll
    for (int i = 0; i < ELEMS; ++i) c += (z[i] > tau) ? 1 : 0;
    int pre = c;
    #pragma unroll
    for (int s = 1; s < 64; s <<= 1) {
        const int t = __shfl_up(pre, s, 64);
        if (lane >= s) pre += t;
    }
    const int K = __shfl(pre, 63, 64);  // total survivors (wave-uniform)
    const int base = pre - c;

    if (K <= CAP) {
        // Compact survivors into wave-private LDS, pull <=SLOTS into regs.
        int idx = base;
        #pragma unroll
        for (int i = 0; i < ELEMS; ++i) {
            if (z[i] > tau) { surv[wave][idx] = z[i]; ++idx; }
        }
        float r[SLOTS];
        #pragma unroll
        for (int j = 0; j < SLOTS; ++j) {
            const int q = lane + 64 * j;
            r[j] = (q < K) ? surv[wave][q] : -2.0f;  // pad contributes 0 for tau >= -1
        }
        for (int it = 0; it < 20; ++it) {
            float s1 = 0.0f, s2 = 0.0f;
            #pragma unroll
            for (int j = 0; j < SLOTS; ++j) {
                const float t = fmaxf(r[j] - tau, 0.0f);
                s1 += t;
                s2 = fmaf(t, t, s2);
            }
            #pragma unroll
            for (int s = 1; s < 64; s <<= 1) {
                s1 += __shfl_xor(s1, s, 64);
                s2 += __shfl_xor(s2, s, 64);
            }
            const float g = s2 - 1.0f;
            tau += g / fmaxf(2.0f * s1, 1e-20f);
            if (fabsf(g) < 1e-7f) break;  // wave-uniform (identical butterfly tree)
        }
    } else {
        // Fallback: full-width Newton (adversarial rows only; correctness net).
        for (int it = 0; it < 30; ++it) {
            float s1 = 0.0f, s2 = 0.0f;
            #pragma unroll
            for (int i = 0; i < ELEMS; ++i) {
                const float t = fmaxf(z[i] - tau, 0.0f);
                s1 += t;
                s2 = fmaf(t, t, s2);
            }
            #pragma unroll
            for (int s = 1; s < 64; s <<= 1) {
                s1 += __shfl_xor(s1, s, 64);
                s2 += __shfl_xor(s2, s, 64);
            }
            const float g = s2 - 1.0f;
            tau += g / fmaxf(2.0f * s1, 1e-20f);
            if (fabsf(g) < 1e-7f) break;
        }
    }

    // p = [z - tau]_+^2 normalized by (sum + 1e-8).
    float ssum = 0.0f;
    #pragma unroll
    for (int i = 0; i < ELEMS; ++i) {
        const float t = fmaxf(z[i] - tau, 0.0f);
        z[i] = t * t;
        ssum += z[i];
    }
    #pragma unroll
    for (int s = 1; s < 64; s <<= 1) ssum += __shfl_xor(ssum, s, 64);
    const float inv = 1.0f / (ssum + 1e-8f);

    #pragma unroll
    for (int k = 0; k < CHUNKS; ++k) {
        float4 v;
        v.x = z[4 * k + 0] * inv;
        v.y = z[4 * k + 1] * inv;
        v.z = z[4 * k + 2] * inv;
        v.w = z[4 * k + 3] * inv;
        *reinterpret_cast<float4*>(orow + (size_t)(k * 64 + lane) * 4) = v;
    }
}

extern "C" void kernel_launch(void* const* d_in, const int* in_sizes, int n_in,
                              void* d_out, int out_size, void* d_ws, size_t ws_size,
                              hipStream_t stream) {
    const float* x = (const float*)d_in[0];
    float* out = (float*)d_out;
    const int rows = in_sizes[0] / ROWLEN;  // 16384
    const int blocks = (rows + ROWS_PER_BLOCK - 1) / ROWS_PER_BLOCK;
    entmax15_rows_kernel<<<blocks, 256, 0, stream>>>(x, out, rows);
}